// Round 12
// baseline (131.414 us; speedup 1.0000x reference)
//
#include <hip/hip_runtime.h>
#include <hip/hip_bf16.h>

#define B_N 8192
#define D_K 256
#define MARGIN 0.3f
#define NBLK2 1040   // 2080 triangular tiles / 2 per block

typedef float f32x4 __attribute__((ext_vector_type(4)));
typedef short s16x8 __attribute__((ext_vector_type(8)));

// Order-preserving float->uint for atomicMax/atomicMin on floats.
__device__ __forceinline__ unsigned fkey(float f) {
    unsigned u = __float_as_uint(f);
    return (u & 0x80000000u) ? ~u : (u | 0x80000000u);
}
__device__ __forceinline__ float kval(unsigned k) {
    return (k & 0x80000000u) ? __uint_as_float(k ^ 0x80000000u)
                             : __uint_as_float(~k);
}

// async 16B global -> LDS (LDS dest = wave-uniform base + lane*16)
__device__ __forceinline__ void load_lds16(const unsigned short* g,
                                           unsigned short* l) {
    __builtin_amdgcn_global_load_lds(
        (const __attribute__((address_space(1))) unsigned int*)g,
        (__attribute__((address_space(3))) unsigned int*)l, 16, 0, 0);
}

// 16-lane (DPP-row) max/min reduction on the VALU pipe; result in lane 15
// of each row-of-16. row_shr:n = 0x110+n.
__device__ __forceinline__ float rowred_max(float v) {
    v = fmaxf(v, __int_as_float(__builtin_amdgcn_update_dpp(
            __float_as_int(v), __float_as_int(v), 0x118, 0xF, 0xF, false)));
    v = fmaxf(v, __int_as_float(__builtin_amdgcn_update_dpp(
            __float_as_int(v), __float_as_int(v), 0x114, 0xF, 0xF, false)));
    v = fmaxf(v, __int_as_float(__builtin_amdgcn_update_dpp(
            __float_as_int(v), __float_as_int(v), 0x112, 0xF, 0xF, false)));
    v = fmaxf(v, __int_as_float(__builtin_amdgcn_update_dpp(
            __float_as_int(v), __float_as_int(v), 0x111, 0xF, 0xF, false)));
    return v;
}
__device__ __forceinline__ float rowred_min(float v) {
    v = fminf(v, __int_as_float(__builtin_amdgcn_update_dpp(
            __float_as_int(v), __float_as_int(v), 0x118, 0xF, 0xF, false)));
    v = fminf(v, __int_as_float(__builtin_amdgcn_update_dpp(
            __float_as_int(v), __float_as_int(v), 0x114, 0xF, 0xF, false)));
    v = fminf(v, __int_as_float(__builtin_amdgcn_update_dpp(
            __float_as_int(v), __float_as_int(v), 0x112, 0xF, 0xF, false)));
    v = fminf(v, __int_as_float(__builtin_amdgcn_update_dpp(
            __float_as_int(v), __float_as_int(v), 0x111, 0xF, 0xF, false)));
    return v;
}

// ---- kernel 1: bf16 round + norms OF ROUNDED VALUES + init ----------------
__global__ __launch_bounds__(256) void prep_kernel(const float* __restrict__ X,
        float* __restrict__ sq, unsigned* __restrict__ apk,
        unsigned* __restrict__ ank, unsigned short* __restrict__ Xp,
        float* __restrict__ acc2) {
    int row  = (blockIdx.x << 2) + (threadIdx.x >> 6);
    int lane = threadIdx.x & 63;
    const float4 v = reinterpret_cast<const float4*>(X + (size_t)row * D_K)[lane];

    float xs[4] = {v.x, v.y, v.z, v.w};
    ushort4 hv;
    unsigned short* hp = &hv.x;
    float s = 0.f;
    #pragma unroll
    for (int i = 0; i < 4; ++i) {
        __hip_bfloat16 h = __float2bfloat16(xs[i]);
        hp[i] = *reinterpret_cast<unsigned short*>(&h);
        float hf = __bfloat162float(h);
        s = fmaf(hf, hf, s);
    }
    *reinterpret_cast<ushort4*>(Xp + (size_t)row * D_K + lane * 4) = hv;

    #pragma unroll
    for (int o = 32; o > 0; o >>= 1) s += __shfl_down(s, o, 64);
    if (lane == 0) {
        sq[row]  = s;
        apk[row] = 0u;           // <= fkey(-inf)
        ank[row] = 0xFFFFFFFFu;  // >= fkey(+inf)
    }
    if (blockIdx.x == 0 && threadIdx.x == 0) {
        acc2[0] = 0.f; acc2[1] = 0.f;
        reinterpret_cast<unsigned*>(acc2)[2] = 0u;   // ticket counter
    }
}

// ---- kernel 2: 2 tiles/block, cross-tile-pipelined dbuf MFMA dist ---------
#define BM 128
#define BN 128
// LDS: 16B unit u of row r at slot S=(r>>1)*8+u*2+(r&1) (128B-line interleave)

__global__ __launch_bounds__(256, 4) void dist_kernel(
        const unsigned short* __restrict__ Xp,
        const int* __restrict__ tgt, const float* __restrict__ sq,
        unsigned* __restrict__ apk, unsigned* __restrict__ ank) {
    __shared__ unsigned short Ab[2][128 * 32];   // 2 x 8 KB
    __shared__ unsigned short Bb[2][128 * 32];   // 2 x 8 KB

    const int t    = threadIdx.x;
    const int lane = t & 63;
    const int wave = t >> 6;
    const int wrow = (wave >> 1) * 64;
    const int wcol = (wave & 1) * 64;
    const int fr   = lane & 15;
    const int quad = lane >> 4;
    const float INF = __int_as_float(0x7f800000);

    // decode two consecutive triangular tiles
    int tt = blockIdx.x * 2;
    int bx = (int)((sqrtf(8.f * (float)tt + 1.f) - 1.f) * 0.5f);
    while ((bx + 1) * (bx + 2) / 2 <= tt) ++bx;
    while (bx * (bx + 1) / 2 > tt) --bx;
    int by = tt - bx * (bx + 1) / 2;
    int bmA[2], bnA[2];
    bmA[0] = by * BM; bnA[0] = bx * BN;
    if (by < bx) { bmA[1] = (by + 1) * BM; bnA[1] = bx * BN; }
    else         { bmA[1] = 0;             bnA[1] = (bx + 1) * BN; }

    // staging lane geometry (tile-independent)
    int rgo[2];    // row offset within tile
    int ugo[2];    // k-unit byte offset (shorts)
    int ldso[2];   // LDS short-offset within buffer
    #pragma unroll
    for (int j = 0; j < 2; ++j) {
        int S   = wave * 64 + j * 256 + lane;   // 0..511
        int l   = S >> 3, idx = S & 7;
        rgo[j]  = l * 2 + (idx & 1);
        ugo[j]  = (idx >> 1) * 8;
        ldso[j] = S * 8;
    }

    f32x4 acc[4][4];

    // prologue: prefetch widx 0 (tile 0, window 0) into buf 0
    #pragma unroll
    for (int j = 0; j < 2; ++j) {
        load_lds16(Xp + (size_t)(bmA[0] + rgo[j]) * D_K + ugo[j],
                   &Ab[0][ldso[j]]);
        load_lds16(Xp + (size_t)(bnA[0] + rgo[j]) * D_K + ugo[j],
                   &Bb[0][ldso[j]]);
    }

    #pragma unroll 1
    for (int widx = 0; widx < 16; ++widx) {
        const int w = widx & 7;
        __syncthreads();   // drains DMA for widx; protects buf (widx+1)&1
        if (widx < 15) {
            const int nx = widx + 1;
            const int nt = nx >> 3;
            const int ko = (nx & 7) * 32;
            #pragma unroll
            for (int j = 0; j < 2; ++j) {
                load_lds16(Xp + (size_t)(bmA[nt] + rgo[j]) * D_K + ko + ugo[j],
                           &Ab[nx & 1][ldso[j]]);
                load_lds16(Xp + (size_t)(bnA[nt] + rgo[j]) * D_K + ko + ugo[j],
                           &Bb[nx & 1][ldso[j]]);
            }
        }
        if (w == 0) {
            #pragma unroll
            for (int i = 0; i < 4; ++i)
                #pragma unroll
                for (int j = 0; j < 4; ++j)
                    acc[i][j] = (f32x4){0.f, 0.f, 0.f, 0.f};
        }

        const unsigned short* At = Ab[widx & 1];
        const unsigned short* Bt = Bb[widx & 1];
        s16x8 a[4], b[4];
        #pragma unroll
        for (int mi = 0; mi < 4; ++mi) {
            int R = wrow + mi * 16 + fr;
            int S = (R >> 1) * 8 + quad * 2 + (R & 1);
            a[mi] = *reinterpret_cast<const s16x8*>(&At[S * 8]);
        }
        #pragma unroll
        for (int ni = 0; ni < 4; ++ni) {
            int R = wcol + ni * 16 + fr;
            int S = (R >> 1) * 8 + quad * 2 + (R & 1);
            b[ni] = *reinterpret_cast<const s16x8*>(&Bt[S * 8]);
        }
        #pragma unroll
        for (int mi = 0; mi < 4; ++mi)
            #pragma unroll
            for (int ni = 0; ni < 4; ++ni)
                acc[mi][ni] = __builtin_amdgcn_mfma_f32_16x16x32_bf16(
                    a[mi], b[ni], acc[mi][ni], 0, 0, 0);

        if (w == 7) {
            // ---- epilogue for tile widx>>3 (no LDS: overlaps next DMA) ----
            const int bm = bmA[widx >> 3];
            const int bn = bnA[widx >> 3];
            int   ct[4]; float csq[4];
            #pragma unroll
            for (int ni = 0; ni < 4; ++ni) {
                int c = bn + wcol + ni * 16 + fr;
                ct[ni] = tgt[c]; csq[ni] = sq[c];
            }
            float cap[4], can[4];
            #pragma unroll
            for (int ni = 0; ni < 4; ++ni) { cap[ni] = -INF; can[ni] = INF; }

            #pragma unroll
            for (int mi = 0; mi < 4; ++mi) {
                #pragma unroll
                for (int reg = 0; reg < 4; ++reg) {
                    int rl = wrow + mi * 16 + quad * 4 + reg;
                    int rt = tgt[bm + rl]; float rsq = sq[bm + rl];
                    float rap = -INF, ran = INF;
                    #pragma unroll
                    for (int ni = 0; ni < 4; ++ni) {
                        float d = rsq + csq[ni] - 2.f * acc[mi][ni][reg];
                        bool pos = (rt == ct[ni]);
                        if (pos) { rap = fmaxf(rap, d); cap[ni] = fmaxf(cap[ni], d); }
                        else     { ran = fminf(ran, d); can[ni] = fminf(can[ni], d); }
                    }
                    rap = rowred_max(rap);
                    ran = rowred_min(ran);
                    if (fr == 15) {
                        atomicMax(&apk[bm + rl], fkey(rap));
                        atomicMin(&ank[bm + rl], fkey(ran));
                    }
                }
            }
            #pragma unroll
            for (int ni = 0; ni < 4; ++ni) {
                #pragma unroll
                for (int o = 16; o < 64; o <<= 1) {
                    cap[ni] = fmaxf(cap[ni], __shfl_xor(cap[ni], o, 64));
                    can[ni] = fminf(can[ni], __shfl_xor(can[ni], o, 64));
                }
            }
            if (lane < 16) {
                #pragma unroll
                for (int ni = 0; ni < 4; ++ni) {
                    int c = bn + wcol + ni * 16 + lane;
                    atomicMax(&apk[c], fkey(cap[ni]));
                    atomicMin(&ank[c], fkey(can[ni]));
                }
            }
        }
    }
}

// ---- kernel 3: loss/prec partial sums + last-block finalize ---------------
__global__ __launch_bounds__(256) void final_kernel(const unsigned* __restrict__ apk,
        const unsigned* __restrict__ ank, float* __restrict__ acc2,
        float* __restrict__ out) {
    __shared__ float s_sum[4], s_cnt[4];
    int i = blockIdx.x * 256 + threadIdx.x;
    float ap = kval(apk[i]);
    float an = kval(ank[i]);
    float v  = ap - an + MARGIN;
    float sum = v > 0.f ? v : 0.f;
    float cnt = an > ap ? 1.f : 0.f;
    #pragma unroll
    for (int o = 32; o > 0; o >>= 1) {
        sum += __shfl_down(sum, o, 64);
        cnt += __shfl_down(cnt, o, 64);
    }
    int wave = threadIdx.x >> 6, lane = threadIdx.x & 63;
    if (lane == 0) { s_sum[wave] = sum; s_cnt[wave] = cnt; }
    __syncthreads();
    if (threadIdx.x == 0) {
        float ts = 0.f, tc = 0.f;
        #pragma unroll
        for (int w = 0; w < 4; ++w) { ts += s_sum[w]; tc += s_cnt[w]; }
        atomicAdd(&acc2[0], ts);
        atomicAdd(&acc2[1], tc);
        __threadfence();
        unsigned ticket = atomicAdd(reinterpret_cast<unsigned*>(acc2) + 2, 1u);
        if (ticket == gridDim.x - 1) {
            float fs = atomicAdd(&acc2[0], 0.f);
            float fc = atomicAdd(&acc2[1], 0.f);
            out[0] = fs / (float)B_N;
            out[1] = fc / (float)B_N;
        }
    }
}

extern "C" void kernel_launch(void* const* d_in, const int* in_sizes, int n_in,
                              void* d_out, int out_size, void* d_ws, size_t ws_size,
                              hipStream_t stream) {
    const float* X   = (const float*)d_in[0];
    const int*   tgt = (const int*)d_in[1];

    char* ws = (char*)d_ws;
    float*          sq   = (float*)ws;                    // 32 KB
    unsigned*       apk  = (unsigned*)(ws + 32768);       // 32 KB
    unsigned*       ank  = (unsigned*)(ws + 65536);       // 32 KB
    float*          acc2 = (float*)(ws + 98304);          // 12 B
    unsigned short* Xp   = (unsigned short*)(ws + 131072);// 4 MB

    float* out = (float*)d_out;

    prep_kernel<<<B_N / 4, 256, 0, stream>>>(X, sq, apk, ank, Xp, acc2);
    dist_kernel<<<NBLK2, 256, 0, stream>>>(Xp, tgt, sq, apk, ank);
    final_kernel<<<B_N / 256, 256, 0, stream>>>(apk, ank, acc2, out);
}